// Round 1
// baseline (887.353 us; speedup 1.0000x reference)
//
#include <hip/hip_runtime.h>
#include <math.h>

#define DSZ 128
#define VOX (DSZ*DSZ*DSZ)  // 2,097,152 voxels
#define PD  130            // padded dim (halo 1 on all 6 faces)

typedef _Float16 half8 __attribute__((ext_vector_type(8)));
typedef _Float16 half4 __attribute__((ext_vector_type(4)));
typedef _Float16 half2v __attribute__((ext_vector_type(2)));
typedef float float4v __attribute__((ext_vector_type(4)));

// Halo-padded tensors: slot(z,y,x) = ((z+1)*130 + (y+1))*130 + (x+1),
// z,y,x in [-1,128]. 8-ch interleaved: halves = slot*8 (33.5 MiB).
// 1-ch: halves = slot (4.2 MiB). Halos zeroed once; interior-only writes.
// WB: interleaved [vox][32] halves (27 taps + 5 pad), 128 MiB.

// ---------------------------------------------------------------------------
// Zero the halo of a padded tensor (ws is re-poisoned before every call).
// ---------------------------------------------------------------------------
template<int CH>
__global__ __launch_bounds__(256) void zero_halo(_Float16* __restrict__ P)
{
    const int t = blockIdx.x * 256 + threadIdx.x;   // (zp,yp) row in [0,130)^2
    if (t >= PD * PD) return;
    const int zp = t / PD;
    const int yp = t - zp * PD;
    _Float16* row = P + (size_t)t * PD * CH;
    if (zp == 0 || zp == PD - 1 || yp == 0 || yp == PD - 1) {
        if (CH == 8) {
            half8 zz = {};
            for (int x = 0; x < PD; ++x) *(half8*)&row[x * 8] = zz;
        } else {
            for (int x = 0; x < PD; ++x) row[x] = (_Float16)0.0f;
        }
    } else {
        if (CH == 8) {
            half8 zz = {};
            *(half8*)&row[0] = zz;
            *(half8*)&row[(PD - 1) * 8] = zz;
        } else {
            row[0] = (_Float16)0.0f;
            row[PD - 1] = (_Float16)0.0f;
        }
    }
}

// ---------------------------------------------------------------------------
// Preformat conv weights -> fp16 [oc][tap(stride 29)][ic], once per launch.
// Blocks: 0..2 = ac{1,2,3}_w1; 3 = out_w; 4 = mid_w; 5..7 = ac{1,2,3}_w2.
// ---------------------------------------------------------------------------
__global__ __launch_bounds__(256) void preformat(const float* __restrict__ w1a, const float* __restrict__ w1b,
                                                 const float* __restrict__ w1c, const float* __restrict__ outw,
                                                 const float* __restrict__ midw,
                                                 const float* __restrict__ w2a, const float* __restrict__ w2b,
                                                 const float* __restrict__ w2c, _Float16* __restrict__ WF)
{
    const int bid = blockIdx.x, tid = threadIdx.x;
    const float* src;
    _Float16* dst;
    int nelem, sz;
    if (bid < 3)       { src = bid == 0 ? w1a : bid == 1 ? w1b : w1c; dst = WF + bid * 3712; nelem = 8 * 216; sz = 16 * 29; }
    else if (bid == 3) { src = outw; dst = WF + 3 * 3712; nelem = 216;     sz = 16 * 29; }
    else if (bid == 4) { src = midw; dst = WF + 4 * 3712; nelem = 8 * 216; sz = 16 * 29; }
    else               { src = bid == 5 ? w2a : bid == 6 ? w2b : w2c; dst = WF + 5 * 3712 + (bid - 5) * 7424; nelem = 27 * 216; sz = 32 * 29; }
    for (int i = tid; i < sz; i += 256) ((half8*)dst)[i] = half8{};
    __syncthreads();
    for (int i = tid; i < nelem; i += 256) {
        const int oc = i / 216;
        const int rem = i - oc * 216;
        const int ic = rem / 27;
        const int tap = rem - ic * 27;
        dst[(oc * 29 + tap) * 8 + ic] = (_Float16)src[i];
    }
}

// ---------------------------------------------------------------------------
// Cast planar fp32 (8ch) -> halo-padded interleaved fp16 (interior only).
// ---------------------------------------------------------------------------
__global__ __launch_bounds__(256) void cast_hp(const float* __restrict__ in,
                                               _Float16* __restrict__ hp)
{
    const int idx = blockIdx.x * 256 + threadIdx.x;
    const int w = idx & 127;
    const int h = (idx >> 7) & 127;
    const int d = idx >> 14;
    half8 v;
    #pragma unroll
    for (int ic = 0; ic < 8; ++ic) v[ic] = (_Float16)in[(size_t)ic * VOX + idx];
    const int slot = ((d + 1) * PD + (h + 1)) * PD + (w + 1);
    *(half8*)&hp[(size_t)slot * 8] = v;
}

// ---------------------------------------------------------------------------
// Dense 3x3x3 conv 8->8 (+bias, opt relu) via MFMA; padded in/out, ROWS=2.
// ---------------------------------------------------------------------------
template<bool RELU>
__global__ __launch_bounds__(256) void conv8x8_mfma(const _Float16* __restrict__ DP,
                                                    const _Float16* __restrict__ WF,
                                                    const float* __restrict__ bias,
                                                    _Float16* __restrict__ HO)
{
    __shared__ _Float16 Wr[16 * 29 * 8];
    const int tid = threadIdx.x;
    for (int i = tid; i < 16 * 29; i += 256) ((half8*)Wr)[i] = ((const half8*)WF)[i];
    __syncthreads();

    const int b = ((blockIdx.x & 7) << 10) | (blockIdx.x >> 3);  // 8192 blocks
    const int h0 = (b & 63) << 1;
    const int d  = b >> 6;
    const int lane = tid & 63;
    const int wv   = tid >> 6;
    const int col  = lane & 15;
    const int q    = lane >> 4;

    half8 af[7];
    #pragma unroll
    for (int c = 0; c < 7; ++c)
        af[c] = *(const half8*)&Wr[(col * 29 + (c * 4 + q)) * 8];

    const int base0 = ((d + 1) * PD + (h0 + 1)) * PD + 1 + wv * 32 + col;
    const _Float16* p[7];
    #pragma unroll
    for (int c = 0; c < 7; ++c) {
        const int tap = min(c * 4 + q, 26);
        const int dz = tap / 9, r9 = tap - dz * 9;
        const int dy = r9 / 3,  dx = r9 - dy * 3;
        p[c] = DP + (size_t)(base0 + ((dz - 1) * PD + (dy - 1)) * PD + (dx - 1)) * 8;
    }

    #pragma unroll
    for (int r = 0; r < 2; ++r) {
        #pragma unroll
        for (int t2 = 0; t2 < 2; ++t2) {
            float4v acc = {0.0f, 0.0f, 0.0f, 0.0f};
            #pragma unroll
            for (int c = 0; c < 7; ++c) {
                const half8 bv = *(const half8*)(p[c] + (r * PD + t2 * 16) * 8);
                acc = __builtin_amdgcn_mfma_f32_16x16x32_f16(af[c], bv, acc, 0, 0, 0);
            }
            if (q < 2) {
                const float4v bl = ((const float4v*)bias)[q];
                half4 hv;
                #pragma unroll
                for (int rr = 0; rr < 4; ++rr) {
                    float v = acc[rr] + bl[rr];
                    if (RELU) v = fmaxf(v, 0.0f);
                    hv[rr] = (_Float16)v;
                }
                *(half4*)&HO[(size_t)(base0 + r * PD + t2 * 16) * 8 + q * 4] = hv;
            }
        }
    }
}

// ---------------------------------------------------------------------------
// Dense 3x3x3 conv 8->1 (+bias) via MFMA; padded in -> padded 1-ch fp16 out.
// ---------------------------------------------------------------------------
__global__ __launch_bounds__(256) void conv8x1_mfma(const _Float16* __restrict__ DP,
                                                    const _Float16* __restrict__ WF,
                                                    const float* __restrict__ bias,
                                                    _Float16* __restrict__ F)
{
    __shared__ _Float16 Wr[16 * 29 * 8];
    const int tid = threadIdx.x;
    for (int i = tid; i < 16 * 29; i += 256) ((half8*)Wr)[i] = ((const half8*)WF)[i];
    __syncthreads();

    const int b = ((blockIdx.x & 7) << 10) | (blockIdx.x >> 3);
    const int h0 = (b & 63) << 1;
    const int d  = b >> 6;
    const int lane = tid & 63;
    const int wv   = tid >> 6;
    const int col  = lane & 15;
    const int q    = lane >> 4;

    half8 af[7];
    #pragma unroll
    for (int c = 0; c < 7; ++c)
        af[c] = *(const half8*)&Wr[(col * 29 + (c * 4 + q)) * 8];

    const int base0 = ((d + 1) * PD + (h0 + 1)) * PD + 1 + wv * 32 + col;
    const _Float16* p[7];
    #pragma unroll
    for (int c = 0; c < 7; ++c) {
        const int tap = min(c * 4 + q, 26);
        const int dz = tap / 9, r9 = tap - dz * 9;
        const int dy = r9 / 3,  dx = r9 - dy * 3;
        p[c] = DP + (size_t)(base0 + ((dz - 1) * PD + (dy - 1)) * PD + (dx - 1)) * 8;
    }

    const float b0 = bias[0];
    #pragma unroll
    for (int r = 0; r < 2; ++r) {
        #pragma unroll
        for (int t2 = 0; t2 < 2; ++t2) {
            float4v acc = {0.0f, 0.0f, 0.0f, 0.0f};
            #pragma unroll
            for (int c = 0; c < 7; ++c) {
                const half8 bv = *(const half8*)(p[c] + (r * PD + t2 * 16) * 8);
                acc = __builtin_amdgcn_mfma_f32_16x16x32_f16(af[c], bv, acc, 0, 0, 0);
            }
            if (q == 0)
                F[base0 + r * PD + t2 * 16] = (_Float16)(acc[0] + b0);
        }
    }
}

// ---------------------------------------------------------------------------
// 8 -> 27 conv + L1 normalize via MFMA; padded in, WB out [vox][32]. ROWS=2.
// (fallback path only)
// ---------------------------------------------------------------------------
__global__ __launch_bounds__(256) void conv8x27n_mfma(const _Float16* __restrict__ HP,
                                                      const _Float16* __restrict__ WF,
                                                      _Float16* __restrict__ WB)
{
    __shared__ _Float16 Wr[32 * 29 * 8];
    const int tid = threadIdx.x;
    for (int i = tid; i < 32 * 29; i += 256) ((half8*)Wr)[i] = ((const half8*)WF)[i];
    __syncthreads();

    const int b = ((blockIdx.x & 7) << 10) | (blockIdx.x >> 3);  // 8192 blocks
    const int h0 = (b & 63) << 1;
    const int d  = b >> 6;
    const int lane = tid & 63;
    const int wv   = tid >> 6;
    const int col  = lane & 15;
    const int q    = lane >> 4;

    half8 af[2][7];
    #pragma unroll
    for (int t = 0; t < 2; ++t)
        #pragma unroll
        for (int c = 0; c < 7; ++c)
            af[t][c] = *(const half8*)&Wr[((t * 16 + col) * 29 + (c * 4 + q)) * 8];

    const int base0 = ((d + 1) * PD + (h0 + 1)) * PD + 1 + wv * 32 + col;
    const _Float16* p[7];
    #pragma unroll
    for (int c = 0; c < 7; ++c) {
        const int tap = min(c * 4 + q, 26);
        const int dz = tap / 9, r9 = tap - dz * 9;
        const int dy = r9 / 3,  dx = r9 - dy * 3;
        p[c] = HP + (size_t)(base0 + ((dz - 1) * PD + (dy - 1)) * PD + (dx - 1)) * 8;
    }

    #pragma unroll
    for (int r = 0; r < 2; ++r) {
        #pragma unroll
        for (int t2 = 0; t2 < 2; ++t2) {
            float4v acc0 = {0.0f, 0.0f, 0.0f, 0.0f};
            float4v acc1 = {0.0f, 0.0f, 0.0f, 0.0f};
            #pragma unroll
            for (int c = 0; c < 7; ++c) {
                const half8 bv = *(const half8*)(p[c] + (r * PD + t2 * 16) * 8);
                acc0 = __builtin_amdgcn_mfma_f32_16x16x32_f16(af[0][c], bv, acc0, 0, 0, 0);
                acc1 = __builtin_amdgcn_mfma_f32_16x16x32_f16(af[1][c], bv, acc1, 0, 0, 0);
            }

            float s = 0.0f;
            #pragma unroll
            for (int rr = 0; rr < 4; ++rr) {
                s += fabsf(acc0[rr]);
                if (16 + q * 4 + rr < 27) s += fabsf(acc1[rr]);
            }
            s += __shfl_xor(s, 16);
            s += __shfl_xor(s, 32);
            const float rcp = 1.0f / fmaxf(s, 1e-12f);

            const int vox = (d << 14) + ((h0 + r) << 7) + wv * 32 + t2 * 16 + col;
            const size_t base = (size_t)vox * 32;
            half4 o0, o1;
            #pragma unroll
            for (int rr = 0; rr < 4; ++rr) {
                o0[rr] = (_Float16)(acc0[rr] * rcp);
                o1[rr] = (_Float16)(acc1[rr] * rcp);   // pad rows write 0
            }
            *(half4*)&WB[base + q * 4]      = o0;
            *(half4*)&WB[base + 16 + q * 4] = o1;
        }
    }
}

// ---------------------------------------------------------------------------
// FUSED: 8 -> 27 conv + L1 normalize -> WB, PLUS first adaptive-conv pass.
// Lane (col,q) holds normalized taps {q*4+rr} (acc0) and {16+q*4+rr} (acc1)
// for voxel col — exactly the 8 taps it applies to XP; cross-q shfl reduce.
// CH=8: XP/OUT padded 8-ch interleaved.  CH=1: padded 1-ch.
// Invalid taps (>=27) carry w==0 (acc1 rows are zero), so no masking.
// ---------------------------------------------------------------------------
template<int CH>
__global__ __launch_bounds__(256) void conv8x27n_aconv(const _Float16* __restrict__ HP,
                                                       const _Float16* __restrict__ WF,
                                                       const _Float16* __restrict__ XP,
                                                       _Float16* __restrict__ WB,
                                                       _Float16* __restrict__ OUT)
{
    __shared__ _Float16 Wr[32 * 29 * 8];
    const int tid = threadIdx.x;
    for (int i = tid; i < 32 * 29; i += 256) ((half8*)Wr)[i] = ((const half8*)WF)[i];
    __syncthreads();

    const int b = ((blockIdx.x & 7) << 10) | (blockIdx.x >> 3);  // 8192 blocks
    const int h0 = (b & 63) << 1;
    const int d  = b >> 6;
    const int lane = tid & 63;
    const int wv   = tid >> 6;
    const int col  = lane & 15;
    const int q    = lane >> 4;

    half8 af[2][7];
    #pragma unroll
    for (int t = 0; t < 2; ++t)
        #pragma unroll
        for (int c = 0; c < 7; ++c)
            af[t][c] = *(const half8*)&Wr[((t * 16 + col) * 29 + (c * 4 + q)) * 8];

    const int base0 = ((d + 1) * PD + (h0 + 1)) * PD + 1 + wv * 32 + col;
    const _Float16* p[7];
    #pragma unroll
    for (int c = 0; c < 7; ++c) {
        const int tap = min(c * 4 + q, 26);
        const int dz = tap / 9, r9 = tap - dz * 9;
        const int dy = r9 / 3,  dx = r9 - dy * 3;
        p[c] = HP + (size_t)(base0 + ((dz - 1) * PD + (dy - 1)) * PD + (dx - 1)) * 8;
    }

    // per-lane stencil tap offsets (element offsets in the padded CH-ch grid)
    int offlo[4], offhi[4];
    #pragma unroll
    for (int rr = 0; rr < 4; ++rr) {
        { const int t = q * 4 + rr;
          const int dz = t / 9, r9 = t - dz * 9, dy = r9 / 3, dx = r9 - dy * 3;
          offlo[rr] = ((dz - 1) * PD + (dy - 1)) * PD + (dx - 1); }
        { const int t = min(16 + q * 4 + rr, 26);      // >=27: w==0, load anything valid
          const int dz = t / 9, r9 = t - dz * 9, dy = r9 / 3, dx = r9 - dy * 3;
          offhi[rr] = ((dz - 1) * PD + (dy - 1)) * PD + (dx - 1); }
    }

    #pragma unroll
    for (int r = 0; r < 2; ++r) {
        #pragma unroll
        for (int t2 = 0; t2 < 2; ++t2) {
            float4v acc0 = {0.0f, 0.0f, 0.0f, 0.0f};
            float4v acc1 = {0.0f, 0.0f, 0.0f, 0.0f};
            #pragma unroll
            for (int c = 0; c < 7; ++c) {
                const half8 bv = *(const half8*)(p[c] + (r * PD + t2 * 16) * 8);
                acc0 = __builtin_amdgcn_mfma_f32_16x16x32_f16(af[0][c], bv, acc0, 0, 0, 0);
                acc1 = __builtin_amdgcn_mfma_f32_16x16x32_f16(af[1][c], bv, acc1, 0, 0, 0);
            }

            float s = 0.0f;
            #pragma unroll
            for (int rr = 0; rr < 4; ++rr) {
                s += fabsf(acc0[rr]);
                if (16 + q * 4 + rr < 27) s += fabsf(acc1[rr]);
            }
            s += __shfl_xor(s, 16);
            s += __shfl_xor(s, 32);
            const float rcp = 1.0f / fmaxf(s, 1e-12f);

            const int vox = (d << 14) + ((h0 + r) << 7) + wv * 32 + t2 * 16 + col;
            const size_t base = (size_t)vox * 32;
            half4 o0, o1;
            #pragma unroll
            for (int rr = 0; rr < 4; ++rr) {
                o0[rr] = (_Float16)(acc0[rr] * rcp);
                o1[rr] = (_Float16)(acc1[rr] * rcp);   // pad rows write 0
            }
            *(half4*)&WB[base + q * 4]      = o0;
            *(half4*)&WB[base + 16 + q * 4] = o1;

            // ---- fused first adaptive-conv pass ----
            const int sslot = base0 + r * PD + t2 * 16;
            if (CH == 8) {
                half2v a4[4];
                #pragma unroll
                for (int j = 0; j < 4; ++j) a4[j] = half2v{};
                #pragma unroll
                for (int rr = 0; rr < 4; ++rr) {
                    const _Float16 wl = o0[rr];
                    const half8 xl = *(const half8*)&XP[(size_t)(sslot + offlo[rr]) * 8];
                    half2v w2l; w2l[0] = wl; w2l[1] = wl;
                    const half2v* xl2 = (const half2v*)&xl;
                    #pragma unroll
                    for (int j = 0; j < 4; ++j) a4[j] += xl2[j] * w2l;

                    const _Float16 wh = o1[rr];
                    const half8 xh = *(const half8*)&XP[(size_t)(sslot + offhi[rr]) * 8];
                    half2v w2h; w2h[0] = wh; w2h[1] = wh;
                    const half2v* xh2 = (const half2v*)&xh;
                    #pragma unroll
                    for (int j = 0; j < 4; ++j) a4[j] += xh2[j] * w2h;
                }
                // reduce partial sums across the 4 q-lanes of this voxel
                #pragma unroll
                for (int j = 0; j < 4; ++j) {
                    int v = *(int*)&a4[j];
                    int u = __shfl_xor(v, 16);
                    a4[j] += *(half2v*)&u;
                    int v2 = *(int*)&a4[j];
                    int u2 = __shfl_xor(v2, 32);
                    a4[j] += *(half2v*)&u2;
                }
                if (q == 0) {
                    half8 o;
                    #pragma unroll
                    for (int j = 0; j < 4; ++j) { o[2 * j] = a4[j][0]; o[2 * j + 1] = a4[j][1]; }
                    *(half8*)&OUT[(size_t)sslot * 8] = o;
                }
            } else {
                float acc = 0.0f;
                #pragma unroll
                for (int rr = 0; rr < 4; ++rr) {
                    acc = fmaf((float)XP[sslot + offlo[rr]], (float)o0[rr], acc);
                    acc = fmaf((float)XP[sslot + offhi[rr]], (float)o1[rr], acc);
                }
                acc += __shfl_xor(acc, 16);
                acc += __shfl_xor(acc, 32);
                if (q == 0) OUT[sslot] = (_Float16)acc;
            }
        }
    }
}

// ---------------------------------------------------------------------------
// Adaptive stencil, 8ch padded interleaved in/out; no boundary logic.
// ---------------------------------------------------------------------------
__global__ __launch_bounds__(256) void aconv8i(const _Float16* __restrict__ in,
                                               const _Float16* __restrict__ wb,
                                               _Float16* __restrict__ out)
{
    const int b = ((blockIdx.x & 7) << 10) | (blockIdx.x >> 3);  // 8192 blocks
    const int idx = b * 256 + threadIdx.x;
    const int w = idx & 127;
    const int h = (idx >> 7) & 127;
    const int d = idx >> 14;

    const size_t wbb = (size_t)idx * 32;
    const half8 wA = *(const half8*)(wb + wbb);
    const half8 wB = *(const half8*)(wb + wbb + 8);
    const half8 wC = *(const half8*)(wb + wbb + 16);
    const half8 wD = *(const half8*)(wb + wbb + 24);

    const int s0 = ((d + 1) * PD + (h + 1)) * PD + (w + 1);

    half2v a4[4];
    #pragma unroll
    for (int j = 0; j < 4; ++j) a4[j] = half2v{};

    #pragma unroll
    for (int dz = 0; dz < 3; dz++) {
        #pragma unroll
        for (int dy = 0; dy < 3; dy++) {
            const _Float16* rp = in + (size_t)(s0 + ((dz - 1) * PD + (dy - 1)) * PD) * 8;
            #pragma unroll
            for (int kw = 0; kw < 3; kw++) {
                const int tap = dz * 9 + dy * 3 + kw;
                const _Float16 wt = (tap < 8) ? wA[tap] : (tap < 16) ? wB[tap - 8]
                                 : (tap < 24) ? wC[tap - 16] : wD[tap - 24];
                half2v w2; w2[0] = wt; w2[1] = wt;
                const half8 hv = *(const half8*)(rp + (kw - 1) * 8);
                const half2v* h2 = (const half2v*)&hv;
                #pragma unroll
                for (int j = 0; j < 4; ++j)
                    a4[j] += h2[j] * w2;                 // v_pk_fma_f16
            }
        }
    }

    half8 o;
    #pragma unroll
    for (int j = 0; j < 4; ++j) { o[2 * j] = a4[j][0]; o[2 * j + 1] = a4[j][1]; }
    *(half8*)&out[(size_t)s0 * 8] = o;
}

// ---------------------------------------------------------------------------
// Adaptive stencil, 1ch padded fp16 in; fp32 math.
// TANH=false: padded fp16 out. TANH=true: planar fp32 out (final).
// ---------------------------------------------------------------------------
template<bool TANH>
__global__ __launch_bounds__(256) void aconv1h(const _Float16* __restrict__ in,
                                               const _Float16* __restrict__ wb,
                                               _Float16* __restrict__ outh,
                                               float* __restrict__ outf)
{
    const int b = ((blockIdx.x & 7) << 10) | (blockIdx.x >> 3);
    const int idx = b * 256 + threadIdx.x;
    const int w = idx & 127;
    const int h = (idx >> 7) & 127;
    const int d = idx >> 14;

    const size_t wbb = (size_t)idx * 32;
    const half8 wA = *(const half8*)(wb + wbb);
    const half8 wB = *(const half8*)(wb + wbb + 8);
    const half8 wC = *(const half8*)(wb + wbb + 16);
    const half8 wD = *(const half8*)(wb + wbb + 24);

    const int s0 = ((d + 1) * PD + (h + 1)) * PD + (w + 1);

    float acc = 0.0f;
    #pragma unroll
    for (int dz = 0; dz < 3; dz++) {
        #pragma unroll
        for (int dy = 0; dy < 3; dy++) {
            const _Float16* rp = in + s0 + ((dz - 1) * PD + (dy - 1)) * PD;
            #pragma unroll
            for (int kw = 0; kw < 3; kw++) {
                const int tap = dz * 9 + dy * 3 + kw;
                const _Float16 wt = (tap < 8) ? wA[tap] : (tap < 16) ? wB[tap - 8]
                                 : (tap < 24) ? wC[tap - 16] : wD[tap - 24];
                acc = fmaf((float)rp[kw - 1], (float)wt, acc);
            }
        }
    }

    if (TANH) outf[idx] = tanhf(acc);
    else      outh[s0] = (_Float16)acc;
}

// ---------------------------------------------------------------------------
// Fused path ws layout (~241 MiB): P0 | P1 | P2 | WB | F1 | G1 | F2 | WF.
// Fallback (old) layout (~208 MiB): P0 | P1 | WB | F1 | G1 | F2 | WF.
// WF halves: [0]=ac1_w1 [3712]=ac2_w1 [7424]=ac3_w1 [11136]=out_w
//   [14848]=mid_w [18560]=ac1_w2 [25984]=ac2_w2 [33408]=ac3_w2
// ---------------------------------------------------------------------------
extern "C" void kernel_launch(void* const* d_in, const int* in_sizes, int n_in,
                              void* d_out, int out_size, void* d_ws, size_t ws_size,
                              hipStream_t stream)
{
    const float* x      = (const float*)d_in[0];
    const float* ac1_w1 = (const float*)d_in[1];
    const float* ac1_b1 = (const float*)d_in[2];
    const float* ac1_w2 = (const float*)d_in[3];
    const float* ac2_w1 = (const float*)d_in[4];
    const float* ac2_b1 = (const float*)d_in[5];
    const float* ac2_w2 = (const float*)d_in[6];
    const float* ac3_w1 = (const float*)d_in[7];
    const float* ac3_b1 = (const float*)d_in[8];
    const float* ac3_w2 = (const float*)d_in[9];
    const float* mid_w  = (const float*)d_in[10];
    const float* mid_b  = (const float*)d_in[11];
    const float* out_w  = (const float*)d_in[12];
    const float* out_b  = (const float*)d_in[13];
    float* out = (float*)d_out;

    char* ws = (char*)d_ws;
    const size_t PS8 = (size_t)PD * PD * PD * 8 * 2;   // 35,152,000 B
    const size_t PS1 = (size_t)PD * PD * PD * 2;       //  4,394,000 B
    const size_t WBsz = (size_t)134217728;
    const size_t WFsz = (size_t)81920;
    const size_t need_fused = 3 * PS8 + WBsz + 3 * PS1 + WFsz;   // 252,937,648 B

    const dim3 blk(256);
    const dim3 gridT(VOX / 256);               // cast, aconv: 8192 blocks
    const dim3 gridM(VOX / 256);               // MFMA convs (ROWS=2): 8192 blocks
    const dim3 gridZ((PD * PD + 255) / 256);   // zero_halo: 67 blocks

    if (ws_size >= need_fused) {
        // ---------------- fused path ----------------
        _Float16* P0 = (_Float16*)(ws);
        _Float16* P1 = (_Float16*)(ws + PS8);
        _Float16* P2 = (_Float16*)(ws + 2 * PS8);
        _Float16* WB = (_Float16*)(ws + 3 * PS8);
        _Float16* F1 = (_Float16*)(ws + 3 * PS8 + WBsz);
        _Float16* G1 = (_Float16*)(ws + 3 * PS8 + WBsz + PS1);
        _Float16* F2 = (_Float16*)(ws + 3 * PS8 + WBsz + 2 * PS1);
        _Float16* WF = (_Float16*)(ws + 3 * PS8 + WBsz + 3 * PS1);
        _Float16* WF8_1  = WF;
        _Float16* WF8_2  = WF + 3712;
        _Float16* WF8_3  = WF + 7424;
        _Float16* WFo    = WF + 11136;
        _Float16* WFmid  = WF + 14848;
        _Float16* WF27_1 = WF + 18560;
        _Float16* WF27_2 = WF + 25984;
        _Float16* WF27_3 = WF + 33408;

        zero_halo<8><<<gridZ, blk, 0, stream>>>(P0);
        zero_halo<8><<<gridZ, blk, 0, stream>>>(P1);
        zero_halo<8><<<gridZ, blk, 0, stream>>>(P2);
        zero_halo<1><<<gridZ, blk, 0, stream>>>(F1);
        zero_halo<1><<<gridZ, blk, 0, stream>>>(G1);
        zero_halo<1><<<gridZ, blk, 0, stream>>>(F2);
        preformat<<<dim3(8), blk, 0, stream>>>(ac1_w1, ac2_w1, ac3_w1, out_w, mid_w,
                                               ac1_w2, ac2_w2, ac3_w2, WF);

        // ---- block 1 ----
        cast_hp<<<gridT, blk, 0, stream>>>(x, P0);                                   // X16 = P0
        conv8x8_mfma<true ><<<gridM, blk, 0, stream>>>(P0, WF8_1, ac1_b1, P1);       // H1 = P1
        conv8x27n_aconv<8><<<gridM, blk, 0, stream>>>(P1, WF27_1, P0, WB, P2);       // WB + c1a = P2
        aconv8i<<<gridT, blk, 0, stream>>>(P2, WB, P0);
        aconv8i<<<gridT, blk, 0, stream>>>(P0, WB, P1);                              // c1 = P1
        // ---- mid conv ----
        conv8x8_mfma<false><<<gridM, blk, 0, stream>>>(P1, WFmid, mid_b, P0);        // M = P0
        // ---- block 2 ----
        conv8x8_mfma<true ><<<gridM, blk, 0, stream>>>(P0, WF8_2, ac2_b1, P1);       // H2 = P1
        conv8x27n_aconv<8><<<gridM, blk, 0, stream>>>(P1, WF27_2, P0, WB, P2);       // WB + c2a = P2
        aconv8i<<<gridT, blk, 0, stream>>>(P2, WB, P0);
        aconv8i<<<gridT, blk, 0, stream>>>(P0, WB, P1);                              // mid2 = P1
        // ---- block 3 (weights from mid2 = P1) ----
        conv8x1_mfma<<<gridM, blk, 0, stream>>>(P1, WFo, out_b, F1);                 // F1
        conv8x8_mfma<true ><<<gridM, blk, 0, stream>>>(P1, WF8_3, ac3_b1, P0);       // H3 = P0
        conv8x27n_aconv<1><<<gridM, blk, 0, stream>>>(P0, WF27_3, F1, WB, G1);       // WB + G1
        aconv1h<false><<<gridT, blk, 0, stream>>>(G1, WB, F2, nullptr);
        aconv1h<true ><<<gridT, blk, 0, stream>>>(F2, WB, nullptr, out);
    } else {
        // ---------------- fallback: previous verified path ----------------
        _Float16* P0 = (_Float16*)(ws);
        _Float16* P1 = (_Float16*)(ws + PS8);
        _Float16* WB = (_Float16*)(ws + 2 * PS8);
        _Float16* F1 = (_Float16*)(ws + 2 * PS8 + WBsz);
        _Float16* G1 = (_Float16*)(ws + 2 * PS8 + WBsz + PS1);
        _Float16* F2 = (_Float16*)(ws + 2 * PS8 + WBsz + 2 * PS1);
        _Float16* WF = (_Float16*)(ws + 2 * PS8 + WBsz + 3 * PS1);
        _Float16* WF8_1  = WF;
        _Float16* WF8_2  = WF + 3712;
        _Float16* WF8_3  = WF + 7424;
        _Float16* WFo    = WF + 11136;
        _Float16* WFmid  = WF + 14848;
        _Float16* WF27_1 = WF + 18560;
        _Float16* WF27_2 = WF + 25984;
        _Float16* WF27_3 = WF + 33408;

        zero_halo<8><<<gridZ, blk, 0, stream>>>(P0);
        zero_halo<8><<<gridZ, blk, 0, stream>>>(P1);
        zero_halo<1><<<gridZ, blk, 0, stream>>>(F1);
        zero_halo<1><<<gridZ, blk, 0, stream>>>(G1);
        zero_halo<1><<<gridZ, blk, 0, stream>>>(F2);
        preformat<<<dim3(8), blk, 0, stream>>>(ac1_w1, ac2_w1, ac3_w1, out_w, mid_w,
                                               ac1_w2, ac2_w2, ac3_w2, WF);

        // ---- block 1 ----
        cast_hp<<<gridT, blk, 0, stream>>>(x, P0);                       // X16 = P0
        conv8x8_mfma<true ><<<gridM, blk, 0, stream>>>(P0, WF8_1, ac1_b1, P1);   // H1
        conv8x27n_mfma<<<gridM, blk, 0, stream>>>(P1, WF27_1, WB);
        aconv8i<<<gridT, blk, 0, stream>>>(P0, WB, P1);                  // (H1 dead)
        aconv8i<<<gridT, blk, 0, stream>>>(P1, WB, P0);
        aconv8i<<<gridT, blk, 0, stream>>>(P0, WB, P1);                  // C1 = P1
        // ---- mid conv ----
        conv8x8_mfma<false><<<gridM, blk, 0, stream>>>(P1, WFmid, mid_b, P0);    // M = P0
        // ---- block 2 ----
        conv8x8_mfma<true ><<<gridM, blk, 0, stream>>>(P0, WF8_2, ac2_b1, P1);   // H2
        conv8x27n_mfma<<<gridM, blk, 0, stream>>>(P1, WF27_2, WB);
        aconv8i<<<gridT, blk, 0, stream>>>(P0, WB, P1);
        aconv8i<<<gridT, blk, 0, stream>>>(P1, WB, P0);
        aconv8i<<<gridT, blk, 0, stream>>>(P0, WB, P1);                  // mid2 = P1
        // ---- block 3 (weights from mid2 = P1) ----
        conv8x8_mfma<true ><<<gridM, blk, 0, stream>>>(P1, WF8_3, ac3_b1, P0);   // H3
        conv8x27n_mfma<<<gridM, blk, 0, stream>>>(P0, WF27_3, WB);
        conv8x1_mfma<<<gridM, blk, 0, stream>>>(P1, WFo, out_b, F1);
        aconv1h<false><<<gridT, blk, 0, stream>>>(F1, WB, G1, nullptr);
        aconv1h<false><<<gridT, blk, 0, stream>>>(G1, WB, F2, nullptr);
        aconv1h<true ><<<gridT, blk, 0, stream>>>(F2, WB, nullptr, out);
    }
}

// Round 2
// 805.547 us; speedup vs baseline: 1.1016x; 1.1016x over previous
//
#include <hip/hip_runtime.h>
#include <math.h>

#define DSZ 128
#define VOX (DSZ*DSZ*DSZ)  // 2,097,152 voxels
#define PD  130            // padded dim (halo 1 on all 6 faces)

typedef _Float16 half8 __attribute__((ext_vector_type(8)));
typedef _Float16 half4 __attribute__((ext_vector_type(4)));
typedef _Float16 half2v __attribute__((ext_vector_type(2)));
typedef float float4v __attribute__((ext_vector_type(4)));

// Halo-padded tensors: slot(z,y,x) = ((z+1)*130 + (y+1))*130 + (x+1),
// z,y,x in [-1,128]. 8-ch interleaved: halves = slot*8 (33.5 MiB).
// 1-ch: halves = slot (4.2 MiB). Halos zeroed once; interior-only writes.
// WB: interleaved [vox][28] halves (27 taps + 1 pad), 112 MiB.
//   tap t lives at halves offset vox*28 + t; tap 27 is pad (never read).

// ---------------------------------------------------------------------------
// Zero the halo of a padded tensor (ws is re-poisoned before every call).
// ---------------------------------------------------------------------------
template<int CH>
__global__ __launch_bounds__(256) void zero_halo(_Float16* __restrict__ P)
{
    const int t = blockIdx.x * 256 + threadIdx.x;   // (zp,yp) row in [0,130)^2
    if (t >= PD * PD) return;
    const int zp = t / PD;
    const int yp = t - zp * PD;
    _Float16* row = P + (size_t)t * PD * CH;
    if (zp == 0 || zp == PD - 1 || yp == 0 || yp == PD - 1) {
        if (CH == 8) {
            half8 zz = {};
            for (int x = 0; x < PD; ++x) *(half8*)&row[x * 8] = zz;
        } else {
            for (int x = 0; x < PD; ++x) row[x] = (_Float16)0.0f;
        }
    } else {
        if (CH == 8) {
            half8 zz = {};
            *(half8*)&row[0] = zz;
            *(half8*)&row[(PD - 1) * 8] = zz;
        } else {
            row[0] = (_Float16)0.0f;
            row[PD - 1] = (_Float16)0.0f;
        }
    }
}

// ---------------------------------------------------------------------------
// Preformat conv weights -> fp16 [oc][tap(stride 29)][ic], once per launch.
// Blocks: 0..2 = ac{1,2,3}_w1; 3 = out_w; 4 = mid_w; 5..7 = ac{1,2,3}_w2.
// ---------------------------------------------------------------------------
__global__ __launch_bounds__(256) void preformat(const float* __restrict__ w1a, const float* __restrict__ w1b,
                                                 const float* __restrict__ w1c, const float* __restrict__ outw,
                                                 const float* __restrict__ midw,
                                                 const float* __restrict__ w2a, const float* __restrict__ w2b,
                                                 const float* __restrict__ w2c, _Float16* __restrict__ WF)
{
    const int bid = blockIdx.x, tid = threadIdx.x;
    const float* src;
    _Float16* dst;
    int nelem, sz;
    if (bid < 3)       { src = bid == 0 ? w1a : bid == 1 ? w1b : w1c; dst = WF + bid * 3712; nelem = 8 * 216; sz = 16 * 29; }
    else if (bid == 3) { src = outw; dst = WF + 3 * 3712; nelem = 216;     sz = 16 * 29; }
    else if (bid == 4) { src = midw; dst = WF + 4 * 3712; nelem = 8 * 216; sz = 16 * 29; }
    else               { src = bid == 5 ? w2a : bid == 6 ? w2b : w2c; dst = WF + 5 * 3712 + (bid - 5) * 7424; nelem = 27 * 216; sz = 32 * 29; }
    for (int i = tid; i < sz; i += 256) ((half8*)dst)[i] = half8{};
    __syncthreads();
    for (int i = tid; i < nelem; i += 256) {
        const int oc = i / 216;
        const int rem = i - oc * 216;
        const int ic = rem / 27;
        const int tap = rem - ic * 27;
        dst[(oc * 29 + tap) * 8 + ic] = (_Float16)src[i];
    }
}

// ---------------------------------------------------------------------------
// Cast planar fp32 (8ch) -> halo-padded interleaved fp16 (interior only).
// ---------------------------------------------------------------------------
__global__ __launch_bounds__(256) void cast_hp(const float* __restrict__ in,
                                               _Float16* __restrict__ hp)
{
    const int idx = blockIdx.x * 256 + threadIdx.x;
    const int w = idx & 127;
    const int h = (idx >> 7) & 127;
    const int d = idx >> 14;
    half8 v;
    #pragma unroll
    for (int ic = 0; ic < 8; ++ic) v[ic] = (_Float16)in[(size_t)ic * VOX + idx];
    const int slot = ((d + 1) * PD + (h + 1)) * PD + (w + 1);
    *(half8*)&hp[(size_t)slot * 8] = v;
}

// ---------------------------------------------------------------------------
// Dense 3x3x3 conv 8->8 (+bias, opt relu) via MFMA; padded in/out, ROWS=2.
// ---------------------------------------------------------------------------
template<bool RELU>
__global__ __launch_bounds__(256) void conv8x8_mfma(const _Float16* __restrict__ DP,
                                                    const _Float16* __restrict__ WF,
                                                    const float* __restrict__ bias,
                                                    _Float16* __restrict__ HO)
{
    __shared__ _Float16 Wr[16 * 29 * 8];
    const int tid = threadIdx.x;
    for (int i = tid; i < 16 * 29; i += 256) ((half8*)Wr)[i] = ((const half8*)WF)[i];
    __syncthreads();

    const int b = ((blockIdx.x & 7) << 10) | (blockIdx.x >> 3);  // 8192 blocks
    const int h0 = (b & 63) << 1;
    const int d  = b >> 6;
    const int lane = tid & 63;
    const int wv   = tid >> 6;
    const int col  = lane & 15;
    const int q    = lane >> 4;

    half8 af[7];
    #pragma unroll
    for (int c = 0; c < 7; ++c)
        af[c] = *(const half8*)&Wr[(col * 29 + (c * 4 + q)) * 8];

    const int base0 = ((d + 1) * PD + (h0 + 1)) * PD + 1 + wv * 32 + col;
    const _Float16* p[7];
    #pragma unroll
    for (int c = 0; c < 7; ++c) {
        const int tap = min(c * 4 + q, 26);
        const int dz = tap / 9, r9 = tap - dz * 9;
        const int dy = r9 / 3,  dx = r9 - dy * 3;
        p[c] = DP + (size_t)(base0 + ((dz - 1) * PD + (dy - 1)) * PD + (dx - 1)) * 8;
    }

    #pragma unroll
    for (int r = 0; r < 2; ++r) {
        #pragma unroll
        for (int t2 = 0; t2 < 2; ++t2) {
            float4v acc = {0.0f, 0.0f, 0.0f, 0.0f};
            #pragma unroll
            for (int c = 0; c < 7; ++c) {
                const half8 bv = *(const half8*)(p[c] + (r * PD + t2 * 16) * 8);
                acc = __builtin_amdgcn_mfma_f32_16x16x32_f16(af[c], bv, acc, 0, 0, 0);
            }
            if (q < 2) {
                const float4v bl = ((const float4v*)bias)[q];
                half4 hv;
                #pragma unroll
                for (int rr = 0; rr < 4; ++rr) {
                    float v = acc[rr] + bl[rr];
                    if (RELU) v = fmaxf(v, 0.0f);
                    hv[rr] = (_Float16)v;
                }
                *(half4*)&HO[(size_t)(base0 + r * PD + t2 * 16) * 8 + q * 4] = hv;
            }
        }
    }
}

// ---------------------------------------------------------------------------
// Dense 3x3x3 conv 8->1 (+bias) via MFMA; padded in -> padded 1-ch fp16 out.
// ---------------------------------------------------------------------------
__global__ __launch_bounds__(256) void conv8x1_mfma(const _Float16* __restrict__ DP,
                                                    const _Float16* __restrict__ WF,
                                                    const float* __restrict__ bias,
                                                    _Float16* __restrict__ F)
{
    __shared__ _Float16 Wr[16 * 29 * 8];
    const int tid = threadIdx.x;
    for (int i = tid; i < 16 * 29; i += 256) ((half8*)Wr)[i] = ((const half8*)WF)[i];
    __syncthreads();

    const int b = ((blockIdx.x & 7) << 10) | (blockIdx.x >> 3);
    const int h0 = (b & 63) << 1;
    const int d  = b >> 6;
    const int lane = tid & 63;
    const int wv   = tid >> 6;
    const int col  = lane & 15;
    const int q    = lane >> 4;

    half8 af[7];
    #pragma unroll
    for (int c = 0; c < 7; ++c)
        af[c] = *(const half8*)&Wr[(col * 29 + (c * 4 + q)) * 8];

    const int base0 = ((d + 1) * PD + (h0 + 1)) * PD + 1 + wv * 32 + col;
    const _Float16* p[7];
    #pragma unroll
    for (int c = 0; c < 7; ++c) {
        const int tap = min(c * 4 + q, 26);
        const int dz = tap / 9, r9 = tap - dz * 9;
        const int dy = r9 / 3,  dx = r9 - dy * 3;
        p[c] = DP + (size_t)(base0 + ((dz - 1) * PD + (dy - 1)) * PD + (dx - 1)) * 8;
    }

    const float b0 = bias[0];
    #pragma unroll
    for (int r = 0; r < 2; ++r) {
        #pragma unroll
        for (int t2 = 0; t2 < 2; ++t2) {
            float4v acc = {0.0f, 0.0f, 0.0f, 0.0f};
            #pragma unroll
            for (int c = 0; c < 7; ++c) {
                const half8 bv = *(const half8*)(p[c] + (r * PD + t2 * 16) * 8);
                acc = __builtin_amdgcn_mfma_f32_16x16x32_f16(af[c], bv, acc, 0, 0, 0);
            }
            if (q == 0)
                F[base0 + r * PD + t2 * 16] = (_Float16)(acc[0] + b0);
        }
    }
}

// ---------------------------------------------------------------------------
// 8 -> 27 conv + L1 normalize via MFMA; padded in, WB out [vox][28]. ROWS=2.
// Lane (col,q): lo half4 = taps q*4..q*4+3; hi half4 = taps 16+q*4.. (q<3).
// q==3 hi covers taps 28..31 — all pad, store skipped.
// ---------------------------------------------------------------------------
__global__ __launch_bounds__(256) void conv8x27n_mfma(const _Float16* __restrict__ HP,
                                                      const _Float16* __restrict__ WF,
                                                      _Float16* __restrict__ WB)
{
    __shared__ _Float16 Wr[32 * 29 * 8];
    const int tid = threadIdx.x;
    for (int i = tid; i < 32 * 29; i += 256) ((half8*)Wr)[i] = ((const half8*)WF)[i];
    __syncthreads();

    const int b = ((blockIdx.x & 7) << 10) | (blockIdx.x >> 3);  // 8192 blocks
    const int h0 = (b & 63) << 1;
    const int d  = b >> 6;
    const int lane = tid & 63;
    const int wv   = tid >> 6;
    const int col  = lane & 15;
    const int q    = lane >> 4;

    half8 af[2][7];
    #pragma unroll
    for (int t = 0; t < 2; ++t)
        #pragma unroll
        for (int c = 0; c < 7; ++c)
            af[t][c] = *(const half8*)&Wr[((t * 16 + col) * 29 + (c * 4 + q)) * 8];

    const int base0 = ((d + 1) * PD + (h0 + 1)) * PD + 1 + wv * 32 + col;
    const _Float16* p[7];
    #pragma unroll
    for (int c = 0; c < 7; ++c) {
        const int tap = min(c * 4 + q, 26);
        const int dz = tap / 9, r9 = tap - dz * 9;
        const int dy = r9 / 3,  dx = r9 - dy * 3;
        p[c] = HP + (size_t)(base0 + ((dz - 1) * PD + (dy - 1)) * PD + (dx - 1)) * 8;
    }

    #pragma unroll
    for (int r = 0; r < 2; ++r) {
        #pragma unroll
        for (int t2 = 0; t2 < 2; ++t2) {
            float4v acc0 = {0.0f, 0.0f, 0.0f, 0.0f};
            float4v acc1 = {0.0f, 0.0f, 0.0f, 0.0f};
            #pragma unroll
            for (int c = 0; c < 7; ++c) {
                const half8 bv = *(const half8*)(p[c] + (r * PD + t2 * 16) * 8);
                acc0 = __builtin_amdgcn_mfma_f32_16x16x32_f16(af[0][c], bv, acc0, 0, 0, 0);
                acc1 = __builtin_amdgcn_mfma_f32_16x16x32_f16(af[1][c], bv, acc1, 0, 0, 0);
            }

            float s = 0.0f;
            #pragma unroll
            for (int rr = 0; rr < 4; ++rr) {
                s += fabsf(acc0[rr]);
                if (16 + q * 4 + rr < 27) s += fabsf(acc1[rr]);
            }
            s += __shfl_xor(s, 16);
            s += __shfl_xor(s, 32);
            const float rcp = 1.0f / fmaxf(s, 1e-12f);

            const int vox = (d << 14) + ((h0 + r) << 7) + wv * 32 + t2 * 16 + col;
            const size_t base = (size_t)vox * 28;
            half4 o0, o1;
            #pragma unroll
            for (int rr = 0; rr < 4; ++rr) {
                o0[rr] = (_Float16)(acc0[rr] * rcp);
                o1[rr] = (_Float16)(acc1[rr] * rcp);   // pad rows produce 0
            }
            *(half4*)&WB[base + q * 4] = o0;
            if (q < 3)
                *(half4*)&WB[base + 16 + q * 4] = o1;  // q==3: taps 28..31, all pad
        }
    }
}

// ---------------------------------------------------------------------------
// Adaptive stencil, 8ch padded interleaved in/out; no boundary logic.
// WB stride 28; weights loaded as 7x half4 (8B aligned at 56B stride).
// ---------------------------------------------------------------------------
__global__ __launch_bounds__(256) void aconv8i(const _Float16* __restrict__ in,
                                               const _Float16* __restrict__ wb,
                                               _Float16* __restrict__ out)
{
    const int b = ((blockIdx.x & 7) << 10) | (blockIdx.x >> 3);  // 8192 blocks
    const int idx = b * 256 + threadIdx.x;
    const int w = idx & 127;
    const int h = (idx >> 7) & 127;
    const int d = idx >> 14;

    const size_t wbb = (size_t)idx * 28;
    half4 W[7];
    #pragma unroll
    for (int k = 0; k < 7; ++k) W[k] = *(const half4*)(wb + wbb + k * 4);

    const int s0 = ((d + 1) * PD + (h + 1)) * PD + (w + 1);

    half2v a4[4];
    #pragma unroll
    for (int j = 0; j < 4; ++j) a4[j] = half2v{};

    #pragma unroll
    for (int dz = 0; dz < 3; dz++) {
        #pragma unroll
        for (int dy = 0; dy < 3; dy++) {
            const _Float16* rp = in + (size_t)(s0 + ((dz - 1) * PD + (dy - 1)) * PD) * 8;
            #pragma unroll
            for (int kw = 0; kw < 3; kw++) {
                const int tap = dz * 9 + dy * 3 + kw;
                const _Float16 wt = W[tap >> 2][tap & 3];
                half2v w2; w2[0] = wt; w2[1] = wt;
                const half8 hv = *(const half8*)(rp + (kw - 1) * 8);
                const half2v* h2 = (const half2v*)&hv;
                #pragma unroll
                for (int j = 0; j < 4; ++j)
                    a4[j] += h2[j] * w2;                 // v_pk_fma_f16
            }
        }
    }

    half8 o;
    #pragma unroll
    for (int j = 0; j < 4; ++j) { o[2 * j] = a4[j][0]; o[2 * j + 1] = a4[j][1]; }
    *(half8*)&out[(size_t)s0 * 8] = o;
}

// ---------------------------------------------------------------------------
// Adaptive stencil, 1ch padded fp16 in; fp32 math. WB stride 28.
// TANH=false: padded fp16 out. TANH=true: planar fp32 out (final).
// ---------------------------------------------------------------------------
template<bool TANH>
__global__ __launch_bounds__(256) void aconv1h(const _Float16* __restrict__ in,
                                               const _Float16* __restrict__ wb,
                                               _Float16* __restrict__ outh,
                                               float* __restrict__ outf)
{
    const int b = ((blockIdx.x & 7) << 10) | (blockIdx.x >> 3);
    const int idx = b * 256 + threadIdx.x;
    const int w = idx & 127;
    const int h = (idx >> 7) & 127;
    const int d = idx >> 14;

    const size_t wbb = (size_t)idx * 28;
    half4 W[7];
    #pragma unroll
    for (int k = 0; k < 7; ++k) W[k] = *(const half4*)(wb + wbb + k * 4);

    const int s0 = ((d + 1) * PD + (h + 1)) * PD + (w + 1);

    float acc = 0.0f;
    #pragma unroll
    for (int dz = 0; dz < 3; dz++) {
        #pragma unroll
        for (int dy = 0; dy < 3; dy++) {
            const _Float16* rp = in + s0 + ((dz - 1) * PD + (dy - 1)) * PD;
            #pragma unroll
            for (int kw = 0; kw < 3; kw++) {
                const int tap = dz * 9 + dy * 3 + kw;
                const _Float16 wt = W[tap >> 2][tap & 3];
                acc = fmaf((float)rp[kw - 1], (float)wt, acc);
            }
        }
    }

    if (TANH) outf[idx] = tanhf(acc);
    else      outh[s0] = (_Float16)acc;
}

// ---------------------------------------------------------------------------
// ws layout (~192 MiB): P0 | P1 (33.5 MiB padded 8-ch each) | WB (112 MiB)
//   | F1 | G1 | F2 (4.2 MiB padded 1-ch each) | WF (preformatted weights).
// WF halves: [0]=ac1_w1 [3712]=ac2_w1 [7424]=ac3_w1 [11136]=out_w
//   [14848]=mid_w [18560]=ac1_w2 [25984]=ac2_w2 [33408]=ac3_w2
// ---------------------------------------------------------------------------
extern "C" void kernel_launch(void* const* d_in, const int* in_sizes, int n_in,
                              void* d_out, int out_size, void* d_ws, size_t ws_size,
                              hipStream_t stream)
{
    const float* x      = (const float*)d_in[0];
    const float* ac1_w1 = (const float*)d_in[1];
    const float* ac1_b1 = (const float*)d_in[2];
    const float* ac1_w2 = (const float*)d_in[3];
    const float* ac2_w1 = (const float*)d_in[4];
    const float* ac2_b1 = (const float*)d_in[5];
    const float* ac2_w2 = (const float*)d_in[6];
    const float* ac3_w1 = (const float*)d_in[7];
    const float* ac3_b1 = (const float*)d_in[8];
    const float* ac3_w2 = (const float*)d_in[9];
    const float* mid_w  = (const float*)d_in[10];
    const float* mid_b  = (const float*)d_in[11];
    const float* out_w  = (const float*)d_in[12];
    const float* out_b  = (const float*)d_in[13];
    float* out = (float*)d_out;

    char* ws = (char*)d_ws;
    const size_t PS8 = (size_t)PD * PD * PD * 8 * 2;   // 35,152,000 B
    const size_t PS1 = (size_t)PD * PD * PD * 2;       //  4,394,000 B
    const size_t WBsz = (size_t)VOX * 28 * 2;          // 117,440,512 B
    _Float16* P0 = (_Float16*)(ws);
    _Float16* P1 = (_Float16*)(ws + PS8);
    _Float16* WB = (_Float16*)(ws + 2 * PS8);
    _Float16* F1 = (_Float16*)(ws + 2 * PS8 + WBsz);
    _Float16* G1 = (_Float16*)(ws + 2 * PS8 + WBsz + PS1);
    _Float16* F2 = (_Float16*)(ws + 2 * PS8 + WBsz + 2 * PS1);
    _Float16* WF = (_Float16*)(ws + 2 * PS8 + WBsz + 3 * PS1);
    _Float16* WF8_1  = WF;
    _Float16* WF8_2  = WF + 3712;
    _Float16* WF8_3  = WF + 7424;
    _Float16* WFo    = WF + 11136;
    _Float16* WFmid  = WF + 14848;
    _Float16* WF27_1 = WF + 18560;
    _Float16* WF27_2 = WF + 25984;
    _Float16* WF27_3 = WF + 33408;

    const dim3 blk(256);
    const dim3 gridT(VOX / 256);               // cast, aconv: 8192 blocks
    const dim3 gridM(VOX / 256);               // MFMA convs (ROWS=2): 8192 blocks
    const dim3 gridZ((PD * PD + 255) / 256);   // zero_halo: 67 blocks

    zero_halo<8><<<gridZ, blk, 0, stream>>>(P0);
    zero_halo<8><<<gridZ, blk, 0, stream>>>(P1);
    zero_halo<1><<<gridZ, blk, 0, stream>>>(F1);
    zero_halo<1><<<gridZ, blk, 0, stream>>>(G1);
    zero_halo<1><<<gridZ, blk, 0, stream>>>(F2);
    preformat<<<dim3(8), blk, 0, stream>>>(ac1_w1, ac2_w1, ac3_w1, out_w, mid_w,
                                           ac1_w2, ac2_w2, ac3_w2, WF);

    // ---- block 1 ----
    cast_hp<<<gridT, blk, 0, stream>>>(x, P0);                       // X16 = P0
    conv8x8_mfma<true ><<<gridM, blk, 0, stream>>>(P0, WF8_1, ac1_b1, P1);   // H1
    conv8x27n_mfma<<<gridM, blk, 0, stream>>>(P1, WF27_1, WB);
    aconv8i<<<gridT, blk, 0, stream>>>(P0, WB, P1);                  // (H1 dead)
    aconv8i<<<gridT, blk, 0, stream>>>(P1, WB, P0);
    aconv8i<<<gridT, blk, 0, stream>>>(P0, WB, P1);                  // C1 = P1
    // ---- mid conv ----
    conv8x8_mfma<false><<<gridM, blk, 0, stream>>>(P1, WFmid, mid_b, P0);    // M = P0
    // ---- block 2 ----
    conv8x8_mfma<true ><<<gridM, blk, 0, stream>>>(P0, WF8_2, ac2_b1, P1);   // H2
    conv8x27n_mfma<<<gridM, blk, 0, stream>>>(P1, WF27_2, WB);
    aconv8i<<<gridT, blk, 0, stream>>>(P0, WB, P1);
    aconv8i<<<gridT, blk, 0, stream>>>(P1, WB, P0);
    aconv8i<<<gridT, blk, 0, stream>>>(P0, WB, P1);                  // mid2 = P1
    // ---- block 3 (weights from mid2 = P1) ----
    conv8x8_mfma<true ><<<gridM, blk, 0, stream>>>(P1, WF8_3, ac3_b1, P0);   // H3
    conv8x27n_mfma<<<gridM, blk, 0, stream>>>(P0, WF27_3, WB);
    conv8x1_mfma<<<gridM, blk, 0, stream>>>(P1, WFo, out_b, F1);
    aconv1h<false><<<gridT, blk, 0, stream>>>(F1, WB, G1, nullptr);
    aconv1h<false><<<gridT, blk, 0, stream>>>(G1, WB, F2, nullptr);
    aconv1h<true ><<<gridT, blk, 0, stream>>>(F2, WB, nullptr, out);
}